// Round 8
// baseline (410.156 us; speedup 1.0000x reference)
//
#include <hip/hip_runtime.h>
#include <hip/hip_fp16.h>

// Problem constants
#define NF 32
#define DM 256
#define HH 128
#define BB 16
#define TT 512
#define BT 8192            // B*T tokens
#define OUT_W_OFF 2097152  // B*T*D
#define EPS 1e-5f

typedef __bf16 bf16x8 __attribute__((ext_vector_type(8)));
typedef float  f32x16 __attribute__((ext_vector_type(16)));
typedef __fp16 f16x2 __attribute__((ext_vector_type(2)));
typedef __fp16 f16x8 __attribute__((ext_vector_type(8)));

__device__ __forceinline__ float eluf(float z){ return z > 0.f ? z : __expf(z) - 1.f; }
__device__ __forceinline__ float sigm(float z){ return 1.f/(1.f + __expf(-z)); }
__device__ __forceinline__ unsigned f2bf(float x){
  unsigned u = __float_as_uint(x);
  u += 0x7fffu + ((u>>16)&1u);   // RNE
  return u>>16;
}
__device__ __forceinline__ float rdlane(float v, int l){
  return __uint_as_float(__builtin_amdgcn_readlane(__float_as_uint(v), l));
}
// broadcast token-indexed value for MFMA C/D row r: m = (r&3)+8*(r>>2)+4*q
__device__ __forceinline__ float qsel(float v, int mb, int lane){
  float a0 = rdlane(v, mb), a1 = rdlane(v, mb+4);
  return (lane & 32) ? a1 : a0;
}

// ---------------- prep: repack w2/wg (f32) -> bf16 B-fragment layout ----------------
// Wpk[f][c][nt][ks][lane][j]: k=ks*16+(lane>>5)*8+j, d=c*32+(lane&31), nt0=proj nt1=gate
__global__ __launch_bounds__(256) void k_prep(const float* __restrict__ w2,
                                              const float* __restrict__ wgm,
                                              uint4* __restrict__ Wpk){
  __shared__ float ssrc[2][128][32];
  const int tid = threadIdx.x;
  const int f = blockIdx.x, c = blockIdx.y;
  #pragma unroll
  for (int it = 0; it < 32; ++it){
    int idx = tid + it*256;
    int arr = idx >> 12;
    int rem = idx & 4095;
    int k = rem >> 5, dd = rem & 31;
    const float* src = arr ? wgm : w2;
    ssrc[arr][k][dd] = src[(f*HH + k)*DM + c*32 + dd];
  }
  __syncthreads();
  #pragma unroll
  for (int p = 0; p < 4; ++p){
    int oc = tid + p*256;
    int nt = oc>>9, ks = (oc>>6)&7, l = oc&63;
    int k0 = ks*16 + (l>>5)*8, dd = l&31;
    float v[8];
    #pragma unroll
    for (int j=0;j<8;++j) v[j] = ssrc[nt][k0+j][dd];
    uint4 pk;
    pk.x = f2bf(v[0]) | (f2bf(v[1])<<16);
    pk.y = f2bf(v[2]) | (f2bf(v[3])<<16);
    pk.z = f2bf(v[4]) | (f2bf(v[5])<<16);
    pk.w = f2bf(v[6]) | (f2bf(v[7])<<16);
    Wpk[(f*8 + c)*1024 + oc] = pk;
  }
}

// ---------------- pass1: GRN + LN, store NORMALIZED shat0=(s-mu)*rs (fp16), pooled ----------------
// stk u4 idx = blk*131072 + c*16384 + f*512 + wid*128 + q*64 + half*32 + col
// fp16 elem j of that u4 = MFMA row r = half*8+j  (token m = (r&3)+8*(r>>2)+4q)
__global__ __launch_bounds__(256, 2) void k_pass1(
    const float* __restrict__ x,  const float* __restrict__ w1, const float* __restrict__ b1,
    const float* __restrict__ b2, const float* __restrict__ bg,
    const float* __restrict__ wsk, const float* __restrict__ bsk,
    const float* __restrict__ lng, const float* __restrict__ lnb,
    const uint4* __restrict__ Wpk,
    float* __restrict__ pooled, uint4* __restrict__ stk4){
  __shared__ float poolbuf[256];
  const int tid = threadIdx.x, lane = tid&63, wid = tid>>6;
  const int col = lane&31, q = lane>>5;
  const int f = blockIdx.y;
  const int tok0 = blockIdx.x*128;
  const int b = tok0 >> 9;
  poolbuf[tid] = 0.f;
  __syncthreads();
  const float xl = x[(tok0 + wid*32 + col)*NF + f];
  // A fragments computed directly in registers (m=col token, k=ks*16+q*8+j)
  bf16x8 afr[8];
  {
    const float* wp = w1 + f*HH + q*8;
    const float* bp = b1 + f*HH + q*8;
    #pragma unroll
    for (int ks=0;ks<8;++ks){
      float4 wa = *(const float4*)(wp + ks*16);
      float4 wb = *(const float4*)(wp + ks*16 + 4);
      float4 ba = *(const float4*)(bp + ks*16);
      float4 bb = *(const float4*)(bp + ks*16 + 4);
      float h0 = eluf(fmaf(xl, wa.x, ba.x));
      float h1 = eluf(fmaf(xl, wa.y, ba.y));
      float h2 = eluf(fmaf(xl, wa.z, ba.z));
      float h3 = eluf(fmaf(xl, wa.w, ba.w));
      float h4 = eluf(fmaf(xl, wb.x, bb.x));
      float h5 = eluf(fmaf(xl, wb.y, bb.y));
      float h6 = eluf(fmaf(xl, wb.z, bb.z));
      float h7 = eluf(fmaf(xl, wb.w, bb.w));
      uint4 pk;
      pk.x = f2bf(h0) | (f2bf(h1)<<16);
      pk.y = f2bf(h2) | (f2bf(h3)<<16);
      pk.z = f2bf(h4) | (f2bf(h5)<<16);
      pk.w = f2bf(h6) | (f2bf(h7)<<16);
      afr[ks] = __builtin_bit_cast(bf16x8, pk);
    }
  }
  float xr[16];
  #pragma unroll
  for (int r=0;r<16;++r) xr[r] = qsel(xl, (r&3)+8*(r>>2), lane);
  float sum[16], ssq[16];
  #pragma unroll
  for (int r=0;r<16;++r){ sum[r]=0.f; ssq[r]=0.f; }
  unsigned spk[8][8];
  #pragma unroll   // CRITICAL: keeps spk[][] in registers (rolled loop -> scratch spill)
  for (int c=0; c<8; ++c){
    const uint4* wb4 = Wpk + (f*8 + c)*1024;
    f32x16 acc0 = {0.f}, acc1 = {0.f};
    #pragma unroll
    for (int ks=0;ks<8;++ks){
      bf16x8 b0 = __builtin_bit_cast(bf16x8, wb4[ks*64 + lane]);
      bf16x8 b1 = __builtin_bit_cast(bf16x8, wb4[512 + ks*64 + lane]);
      acc0 = __builtin_amdgcn_mfma_f32_32x32x16_bf16(afr[ks], b0, acc0, 0,0,0);
      acc1 = __builtin_amdgcn_mfma_f32_32x32x16_bf16(afr[ks], b1, acc1, 0,0,0);
    }
    const int d = c*32 + col;
    const float b2v = b2[f*DM+d], bgv = bg[f*DM+d];
    const float wsv = wsk[f*DM+d], bsv = bsk[f*DM+d];
    #pragma unroll
    for (int i=0;i<8;++i){
      const int r0 = 2*i, r1 = 2*i+1;
      float sv0 = fmaf(xr[r0], wsv, bsv) + sigm(acc1[r0]+bgv)*(acc0[r0]+b2v);
      float sv1 = fmaf(xr[r1], wsv, bsv) + sigm(acc1[r1]+bgv)*(acc0[r1]+b2v);
      sum[r0] += sv0; ssq[r0] = fmaf(sv0, sv0, ssq[r0]);
      sum[r1] += sv1; ssq[r1] = fmaf(sv1, sv1, ssq[r1]);
      spk[c][i] = __builtin_bit_cast(unsigned, __builtin_amdgcn_cvt_pkrtz(sv0, sv1));
    }
  }
  // LN stats: butterfly over 32 cols within each q-half -> mu in sum[], rs in ssq[]
  #pragma unroll
  for (int r=0;r<16;++r){
    float s1 = sum[r], s2 = ssq[r];
    s1 += __shfl_xor(s1,1);  s2 += __shfl_xor(s2,1);
    s1 += __shfl_xor(s1,2);  s2 += __shfl_xor(s2,2);
    s1 += __shfl_xor(s1,4);  s2 += __shfl_xor(s2,4);
    s1 += __shfl_xor(s1,8);  s2 += __shfl_xor(s2,8);
    s1 += __shfl_xor(s1,16); s2 += __shfl_xor(s2,16);
    float mu = s1 * (1.f/256.f);
    float var = fmaf(-mu, mu, s2*(1.f/256.f));
    sum[r] = mu;
    ssq[r] = rsqrtf(fmaxf(var, 0.f) + EPS);
  }
  // normalize in-register, store shat0 fp16 (coalesced), pool sums
  const size_t sbase = (size_t)blockIdx.x*131072 + (size_t)f*512
                     + (size_t)(wid*128 + q*64 + col);
  #pragma unroll
  for (int c=0;c<8;++c){
    float sh[16];
    unsigned rp[8];
    #pragma unroll
    for (int i=0;i<8;++i){
      f16x2 pr = __builtin_bit_cast(f16x2, spk[c][i]);
      float s0 = (float)pr[0], s1 = (float)pr[1];
      sh[2*i]   = (s0 - sum[2*i  ]) * ssq[2*i  ];
      sh[2*i+1] = (s1 - sum[2*i+1]) * ssq[2*i+1];
      rp[i] = __builtin_bit_cast(unsigned, __builtin_amdgcn_cvt_pkrtz(sh[2*i], sh[2*i+1]));
    }
    uint4 u0, u1;
    u0.x = rp[0]; u0.y = rp[1]; u0.z = rp[2]; u0.w = rp[3];
    u1.x = rp[4]; u1.y = rp[5]; u1.z = rp[6]; u1.w = rp[7];
    stk4[sbase + c*16384     ] = u0;
    stk4[sbase + c*16384 + 32] = u1;
    float ps = 0.f;
    #pragma unroll
    for (int r=0;r<16;++r) ps += sh[r];
    ps += __shfl_xor(ps, 32);
    if (lane < 32) atomicAdd(&poolbuf[c*32 + col], ps);
  }
  __syncthreads();
  const float contrib = fmaf(lng[f*DM+tid], poolbuf[tid], 128.f*lnb[f*DM+tid]);
  atomicAdd(&pooled[b*8192 + f*DM + tid], contrib);
}

// ---------------- pass2a: flat_pooled @ W1 / @ Ws — W1 read ONCE (16 k-slice blocks) ----------------
__global__ __launch_bounds__(256) void k_pass2a(const float* __restrict__ pooled,
    const float* __restrict__ W1, const float* __restrict__ Wsm,
    float* __restrict__ hw_pre, float* __restrict__ sk_pre){
  __shared__ float fl[16][512];   // 32 KB: all batches, this k-slice
  const int tid = threadIdx.x;
  const int k0 = blockIdx.x * 512;
  #pragma unroll
  for (int p = 0; p < 32; ++p){
    int e = tid + p*256;
    int bb = e >> 9, kk = e & 511;
    fl[bb][kk] = pooled[bb*8192 + k0 + kk] * (1.f/512.f);
  }
  __syncthreads();
  // W1 path: thread owns output col tid
  float acc[16];
  #pragma unroll
  for (int bb=0;bb<16;++bb) acc[bb]=0.f;
  const float* wcol = W1 + (size_t)k0*DM + tid;
  #pragma unroll 4
  for (int i=0;i<512;++i){
    float w = wcol[(size_t)i*DM];
    #pragma unroll
    for (int bb=0;bb<16;++bb) acc[bb] = fmaf(fl[bb][i], w, acc[bb]);
  }
  #pragma unroll
  for (int bb=0;bb<16;++bb) atomicAdd(&hw_pre[bb*DM + tid], acc[bb]);
  // Ws path: colj 0..31, sub covers 64-k subranges
  const int colj = tid & 31, sub = tid >> 5;
  float acc2[16];
  #pragma unroll
  for (int bb=0;bb<16;++bb) acc2[bb]=0.f;
  const float* wscol = Wsm + (size_t)(k0 + sub*64)*NF + colj;
  #pragma unroll 4
  for (int i=0;i<64;++i){
    float w = wscol[(size_t)i*NF];
    #pragma unroll
    for (int bb=0;bb<16;++bb) acc2[bb] = fmaf(fl[bb][sub*64+i], w, acc2[bb]);
  }
  #pragma unroll
  for (int bb=0;bb<16;++bb) atomicAdd(&sk_pre[bb*NF + colj], acc2[bb]);
}

// ---------------- pass2b: weight GRN + LN + softmax -> weights ----------------
__global__ __launch_bounds__(64) void k_pass2b(const float* __restrict__ hw_pre, const float* __restrict__ sk_pre,
    const float* __restrict__ B1, const float* __restrict__ W2, const float* __restrict__ B2,
    const float* __restrict__ Wg, const float* __restrict__ Bg, const float* __restrict__ Bs,
    const float* __restrict__ LNg, const float* __restrict__ LNb,
    float* __restrict__ out, float* __restrict__ wsel){
  __shared__ float hw[256];
  const int tid = threadIdx.x, b = blockIdx.x;
  for (int i=tid;i<256;i+=64) hw[i] = eluf(hw_pre[b*DM+i] + B1[i]);
  __syncthreads();
  if (tid < 32){
    const int j = tid;
    float ap = B2[j], ag = Bg[j];
    #pragma unroll 4
    for (int i=0;i<256;++i){ float h = hw[i]; ap = fmaf(h, W2[i*NF+j], ap); ag = fmaf(h, Wg[i*NF+j], ag); }
    float gw = sigm(ag);
    float v = sk_pre[b*NF+j] + Bs[j] + gw*ap;
    float s1 = v;
    s1 += __shfl_xor(s1,1); s1 += __shfl_xor(s1,2); s1 += __shfl_xor(s1,4); s1 += __shfl_xor(s1,8); s1 += __shfl_xor(s1,16);
    float mean = s1*(1.f/32.f);
    float dv = v - mean;
    float s2 = dv*dv;
    s2 += __shfl_xor(s2,1); s2 += __shfl_xor(s2,2); s2 += __shfl_xor(s2,4); s2 += __shfl_xor(s2,8); s2 += __shfl_xor(s2,16);
    float wn = fmaf(dv * rsqrtf(s2*(1.f/32.f) + EPS), LNg[j], LNb[j]);
    float mx = wn;
    mx = fmaxf(mx, __shfl_xor(mx,1)); mx = fmaxf(mx, __shfl_xor(mx,2)); mx = fmaxf(mx, __shfl_xor(mx,4));
    mx = fmaxf(mx, __shfl_xor(mx,8)); mx = fmaxf(mx, __shfl_xor(mx,16));
    float e = __expf(wn - mx);
    float se = e;
    se += __shfl_xor(se,1); se += __shfl_xor(se,2); se += __shfl_xor(se,4); se += __shfl_xor(se,8); se += __shfl_xor(se,16);
    float wgt = e / se;
    out[OUT_W_OFF + b*NF + j] = wgt;
    wsel[b*NF + j] = wgt;
  }
}

// ---------------- combine: out[t,d] = sum_f (wf*g[f,d])*shat0 + sum_f wf*b[f,d] ----------------
// block = (blk64, c8); reads are one contiguous 256 KB stream (f-stride 8 KB).
__global__ __launch_bounds__(512) void k_comb(const uint4* __restrict__ stk4,
    const float* __restrict__ wsel, const float* __restrict__ lng, const float* __restrict__ lnb,
    float* __restrict__ out){
  __shared__ float coefL[NF*32];   // wf * g[f,d]  (4 KB)
  __shared__ float C1[32];         // sum_f wf * b[f,d]
  const int tid = threadIdx.x;
  const int bi = blockIdx.x;
  const int blk = bi>>3, c = bi&7;
  const int b = blk>>2;
  for (int e = tid; e < NF*32; e += 512){
    int fe = e>>5, dd = e&31;
    coefL[e] = wsel[b*NF+fe] * lng[fe*DM + c*32 + dd];
  }
  if (tid < 32){
    float s = 0.f;
    #pragma unroll 4
    for (int fe=0; fe<NF; ++fe) s = fmaf(wsel[b*NF+fe], lnb[fe*DM + c*32 + tid], s);
    C1[tid] = s;
  }
  __syncthreads();
  const int col = tid&31, half = (tid>>5)&1, q = (tid>>6)&1, wid = (tid>>7)&3;
  const size_t base = (size_t)blk*131072 + (size_t)c*16384 + (size_t)tid;
  float acc[8];
  #pragma unroll
  for (int j=0;j<8;++j) acc[j]=0.f;
  #pragma unroll 8
  for (int f=0; f<NF; ++f){
    uint4 v = stk4[base + (size_t)f*512];
    float cf = coefL[f*32 + col];
    f16x8 s8 = __builtin_bit_cast(f16x8, v);
    #pragma unroll
    for (int j=0;j<8;++j) acc[j] = fmaf(cf, (float)s8[j], acc[j]);
  }
  const float c1 = C1[col];
  const int tokw = blk*128 + wid*32;
  #pragma unroll
  for (int j=0;j<8;++j){
    int r = half*8 + j;
    int m = (r&3) + 8*(r>>2) + 4*q;
    out[(size_t)(tokw + m)*DM + c*32 + col] = acc[j] + c1;
  }
}

extern "C" void kernel_launch(void* const* d_in, const int* in_sizes, int n_in,
                              void* d_out, int out_size, void* d_ws, size_t ws_size,
                              hipStream_t stream) {
  const float* x   = (const float*)d_in[0];
  const float* w1  = (const float*)d_in[1];
  const float* b1  = (const float*)d_in[2];
  const float* w2  = (const float*)d_in[3];
  const float* b2  = (const float*)d_in[4];
  const float* wgm = (const float*)d_in[5];
  const float* bg  = (const float*)d_in[6];
  const float* wsk = (const float*)d_in[7];
  const float* bsk = (const float*)d_in[8];
  const float* lng = (const float*)d_in[9];
  const float* lnb = (const float*)d_in[10];
  const float* W1  = (const float*)d_in[11];
  const float* B1  = (const float*)d_in[12];
  const float* W2  = (const float*)d_in[13];
  const float* B2  = (const float*)d_in[14];
  const float* Wg  = (const float*)d_in[15];
  const float* Bg  = (const float*)d_in[16];
  const float* Wsm = (const float*)d_in[17];
  const float* Bs  = (const float*)d_in[18];
  const float* LNg = (const float*)d_in[19];
  const float* LNb = (const float*)d_in[20];
  float* out = (float*)d_out;

  char* ws = (char*)d_ws;
  uint4* Wpk    = (uint4*)ws;                     // 4 MiB bf16-packed weights
  uint4* stk4   = (uint4*)(ws + 4194304);         // 128 MiB fp16 normalized shat0
  float* pooled = (float*)(ws + 138412032);       // 512 KiB
  float* hw_pre = (float*)(ws + 138936320);       // 16 KiB
  float* sk_pre = (float*)(ws + 138952704);       // 2 KiB
  float* wsel   = (float*)(ws + 138954752);       // 2 KiB

  (void)hipMemsetAsync(pooled, 0, 524288 + 16384 + 2048, stream);

  k_prep<<<dim3(32,8), 256, 0, stream>>>(w2, wgm, Wpk);
  k_pass1<<<dim3(64,32), 256, 0, stream>>>(x, w1, b1, b2, bg, wsk, bsk, lng, lnb,
                                           Wpk, pooled, stk4);
  k_pass2a<<<16, 256, 0, stream>>>(pooled, W1, Wsm, hw_pre, sk_pre);
  k_pass2b<<<16, 64, 0, stream>>>(hw_pre, sk_pre, B1, W2, B2, Wg, Bg, Bs, LNg, LNb, out, wsel);
  k_comb<<<512, 512, 0, stream>>>(stk4, wsel, lng, lnb, out);
}

// Round 9
// 332.735 us; speedup vs baseline: 1.2327x; 1.2327x over previous
//
#include <hip/hip_runtime.h>
#include <hip/hip_fp16.h>

// Problem constants
#define NF 32
#define DM 256
#define HH 128
#define BB 16
#define TT 512
#define BT 8192            // B*T tokens
#define OUT_W_OFF 2097152  // B*T*D
#define EPS 1e-5f

typedef __bf16 bf16x8 __attribute__((ext_vector_type(8)));
typedef float  f32x16 __attribute__((ext_vector_type(16)));
typedef __fp16 f16x2 __attribute__((ext_vector_type(2)));
typedef __fp16 f16x8 __attribute__((ext_vector_type(8)));

__device__ __forceinline__ float eluf(float z){ return z > 0.f ? z : __expf(z) - 1.f; }
__device__ __forceinline__ float sigm(float z){ return 1.f/(1.f + __expf(-z)); }
__device__ __forceinline__ unsigned f2bf(float x){
  unsigned u = __float_as_uint(x);
  u += 0x7fffu + ((u>>16)&1u);   // RNE
  return u>>16;
}
__device__ __forceinline__ float rdlane(float v, int l){
  return __uint_as_float(__builtin_amdgcn_readlane(__float_as_uint(v), l));
}
// broadcast token-indexed value for MFMA C/D row r: m = (r&3)+8*(r>>2)+4*q
__device__ __forceinline__ float qsel(float v, int mb, int lane){
  float a0 = rdlane(v, mb), a1 = rdlane(v, mb+4);
  return (lane & 32) ? a1 : a0;
}

// ---------------- prep: repack w2/wg (f32) -> bf16 B-fragment layout ----------------
// Wpk[f][c][nt][ks][lane][j]: k=ks*16+(lane>>5)*8+j, d=c*32+(lane&31), nt0=proj nt1=gate
__global__ __launch_bounds__(256) void k_prep(const float* __restrict__ w2,
                                              const float* __restrict__ wgm,
                                              uint4* __restrict__ Wpk){
  __shared__ float ssrc[2][128][32];
  const int tid = threadIdx.x;
  const int f = blockIdx.x, c = blockIdx.y;
  #pragma unroll
  for (int it = 0; it < 32; ++it){
    int idx = tid + it*256;
    int arr = idx >> 12;
    int rem = idx & 4095;
    int k = rem >> 5, dd = rem & 31;
    const float* src = arr ? wgm : w2;
    ssrc[arr][k][dd] = src[(f*HH + k)*DM + c*32 + dd];
  }
  __syncthreads();
  #pragma unroll
  for (int p = 0; p < 4; ++p){
    int oc = tid + p*256;
    int nt = oc>>9, ks = (oc>>6)&7, l = oc&63;
    int k0 = ks*16 + (l>>5)*8, dd = l&31;
    float v[8];
    #pragma unroll
    for (int j=0;j<8;++j) v[j] = ssrc[nt][k0+j][dd];
    uint4 pk;
    pk.x = f2bf(v[0]) | (f2bf(v[1])<<16);
    pk.y = f2bf(v[2]) | (f2bf(v[3])<<16);
    pk.z = f2bf(v[4]) | (f2bf(v[5])<<16);
    pk.w = f2bf(v[6]) | (f2bf(v[7])<<16);
    Wpk[(f*8 + c)*1024 + oc] = pk;
  }
}

// ---------------- pass1: block = 32 tokens x 1 feature; waves split d (2 chunks each) ----------------
// stk layout [tgrp(64)][f(32)][toct(16)][d(256)] of uint4:
//   idx = tgrp*131072 + f*4096 + toct*256 + d,  toct = loc4*4 + q*2 + half
//   fp16 elem j = token loc4*32 + (j&3) + 16*half + 8*(j>>2) + 4*q   (normalized shat0)
__global__ void k_pass1(
    const float* __restrict__ x,  const float* __restrict__ w1, const float* __restrict__ b1,
    const float* __restrict__ b2, const float* __restrict__ bg,
    const float* __restrict__ wsk, const float* __restrict__ bsk,
    const float* __restrict__ lng, const float* __restrict__ lnb,
    const uint4* __restrict__ Wpk,
    float* __restrict__ pooled, uint4* __restrict__ stk4){
  __shared__ float sumL[128], ssqL[128];
  __shared__ float muL[32], rsL[32];
  const int tid = threadIdx.x, lane = tid&63, wid = tid>>6;
  const int col = lane&31, q = lane>>5;
  const int f = blockIdx.y;
  const int tb = blockIdx.x;           // 0..255 token-block of 32
  const int tok0 = tb*32;
  const int b = tb >> 4;
  const int tgrp = tb >> 2, loc4 = tb & 3;
  const float xl = x[(tok0 + col)*NF + f];
  // A fragments in registers (token m = col, k = ks*16 + q*8 + j) — same for all 4 waves
  bf16x8 afr[8];
  {
    const float* wp = w1 + f*HH + q*8;
    const float* bp = b1 + f*HH + q*8;
    #pragma unroll
    for (int ks=0;ks<8;++ks){
      float4 wa = *(const float4*)(wp + ks*16);
      float4 wb = *(const float4*)(wp + ks*16 + 4);
      float4 ba = *(const float4*)(bp + ks*16);
      float4 bb = *(const float4*)(bp + ks*16 + 4);
      float h0 = eluf(fmaf(xl, wa.x, ba.x));
      float h1 = eluf(fmaf(xl, wa.y, ba.y));
      float h2 = eluf(fmaf(xl, wa.z, ba.z));
      float h3 = eluf(fmaf(xl, wa.w, ba.w));
      float h4 = eluf(fmaf(xl, wb.x, bb.x));
      float h5 = eluf(fmaf(xl, wb.y, bb.y));
      float h6 = eluf(fmaf(xl, wb.z, bb.z));
      float h7 = eluf(fmaf(xl, wb.w, bb.w));
      uint4 pk;
      pk.x = f2bf(h0) | (f2bf(h1)<<16);
      pk.y = f2bf(h2) | (f2bf(h3)<<16);
      pk.z = f2bf(h4) | (f2bf(h5)<<16);
      pk.w = f2bf(h6) | (f2bf(h7)<<16);
      afr[ks] = __builtin_bit_cast(bf16x8, pk);
    }
  }
  float xr[16];
  #pragma unroll
  for (int r=0;r<16;++r) xr[r] = qsel(xl, (r&3)+8*(r>>2), lane);
  float sum[16], ssq[16];
  #pragma unroll
  for (int r=0;r<16;++r){ sum[r]=0.f; ssq[r]=0.f; }
  unsigned spk[2][8];                  // only 2 chunks per wave -> 16 VGPRs, no spill
  const int c0 = wid*2;
  #pragma unroll
  for (int cc=0; cc<2; ++cc){
    const int c = c0 + cc;
    const uint4* wb4 = Wpk + (f*8 + c)*1024;
    f32x16 acc0 = {0.f}, acc1 = {0.f};
    #pragma unroll
    for (int ks=0;ks<8;++ks){
      bf16x8 b0 = __builtin_bit_cast(bf16x8, wb4[ks*64 + lane]);
      bf16x8 b1f = __builtin_bit_cast(bf16x8, wb4[512 + ks*64 + lane]);
      acc0 = __builtin_amdgcn_mfma_f32_32x32x16_bf16(afr[ks], b0, acc0, 0,0,0);
      acc1 = __builtin_amdgcn_mfma_f32_32x32x16_bf16(afr[ks], b1f, acc1, 0,0,0);
    }
    const int d = c*32 + col;
    const float b2v = b2[f*DM+d], bgv = bg[f*DM+d];
    const float wsv = wsk[f*DM+d], bsv = bsk[f*DM+d];
    #pragma unroll
    for (int i=0;i<8;++i){
      const int r0 = 2*i, r1 = 2*i+1;
      float sv0 = fmaf(xr[r0], wsv, bsv) + sigm(acc1[r0]+bgv)*(acc0[r0]+b2v);
      float sv1 = fmaf(xr[r1], wsv, bsv) + sigm(acc1[r1]+bgv)*(acc0[r1]+b2v);
      sum[r0] += sv0; ssq[r0] = fmaf(sv0, sv0, ssq[r0]);
      sum[r1] += sv1; ssq[r1] = fmaf(sv1, sv1, ssq[r1]);
      spk[cc][i] = __builtin_bit_cast(unsigned, __builtin_amdgcn_cvt_pkrtz(sv0, sv1));
    }
  }
  // intra-wave butterfly over 32 cols in each q-half: per-row partials over this wave's 64 d
  #pragma unroll
  for (int r=0;r<16;++r){
    float s1 = sum[r], s2 = ssq[r];
    s1 += __shfl_xor(s1,1);  s2 += __shfl_xor(s2,1);
    s1 += __shfl_xor(s1,2);  s2 += __shfl_xor(s2,2);
    s1 += __shfl_xor(s1,4);  s2 += __shfl_xor(s2,4);
    s1 += __shfl_xor(s1,8);  s2 += __shfl_xor(s2,8);
    s1 += __shfl_xor(s1,16); s2 += __shfl_xor(s2,16);
    sum[r] = s1; ssq[r] = s2;
  }
  if (col == 0){
    #pragma unroll
    for (int r=0;r<16;++r){
      sumL[wid*32 + q*16 + r] = sum[r];
      ssqL[wid*32 + q*16 + r] = ssq[r];
    }
  }
  __syncthreads();
  // cross-wave reduce: thread m (0..31) owns token m
  if (tid < 32){
    const int m = tid;
    const int qq = (m>>2)&1;
    const int rr = (m&3) + ((m>>3)<<2);
    float s1 = 0.f, s2 = 0.f;
    #pragma unroll
    for (int w=0;w<4;++w){ s1 += sumL[w*32+qq*16+rr]; s2 += ssqL[w*32+qq*16+rr]; }
    float mu = s1 * (1.f/256.f);
    float var = fmaf(-mu, mu, s2*(1.f/256.f));
    muL[m] = mu;
    rsL[m] = rsqrtf(fmaxf(var, 0.f) + EPS);
  }
  __syncthreads();
  float mur[16], rsr[16];
  #pragma unroll
  for (int r=0;r<16;++r){
    int m = (r&3) + 8*(r>>2) + 4*q;
    mur[r] = muL[m];
    rsr[r] = rsL[m];
  }
  // normalize, store shat0 fp16, pooled via identity
  const size_t sbase = (size_t)tgrp*131072 + (size_t)f*4096 + (size_t)(loc4*4 + q*2)*256;
  #pragma unroll
  for (int cc=0; cc<2; ++cc){
    const int c = c0 + cc;
    const int d = c*32 + col;
    float sh[16];
    unsigned rp[8];
    #pragma unroll
    for (int i=0;i<8;++i){
      f16x2 pr = __builtin_bit_cast(f16x2, spk[cc][i]);
      sh[2*i]   = ((float)pr[0] - mur[2*i  ]) * rsr[2*i  ];
      sh[2*i+1] = ((float)pr[1] - mur[2*i+1]) * rsr[2*i+1];
      rp[i] = __builtin_bit_cast(unsigned, __builtin_amdgcn_cvt_pkrtz(sh[2*i], sh[2*i+1]));
    }
    uint4 u0, u1;
    u0.x = rp[0]; u0.y = rp[1]; u0.z = rp[2]; u0.w = rp[3];
    u1.x = rp[4]; u1.y = rp[5]; u1.z = rp[6]; u1.w = rp[7];
    stk4[sbase + d      ] = u0;   // half 0
    stk4[sbase + 256 + d] = u1;   // half 1
    float ps = 0.f;
    #pragma unroll
    for (int r=0;r<16;++r) ps += sh[r];
    ps += __shfl_xor(ps, 32);     // add other q-half -> sum over all 32 tokens
    if (q == 0){
      const float gv = lng[f*DM+d], bv = lnb[f*DM+d];
      atomicAdd(&pooled[b*8192 + f*DM + d], fmaf(32.f, bv, gv*ps));
    }
  }
}

// ---------------- pass2a: flat_pooled @ W1 / @ Ws — W1 read ONCE (16 k-slice blocks) ----------------
__global__ __launch_bounds__(256) void k_pass2a(const float* __restrict__ pooled,
    const float* __restrict__ W1, const float* __restrict__ Wsm,
    float* __restrict__ hw_pre, float* __restrict__ sk_pre){
  __shared__ float fl[16][512];   // 32 KB: all batches, this k-slice
  const int tid = threadIdx.x;
  const int k0 = blockIdx.x * 512;
  #pragma unroll
  for (int p = 0; p < 32; ++p){
    int e = tid + p*256;
    int bb = e >> 9, kk = e & 511;
    fl[bb][kk] = pooled[bb*8192 + k0 + kk] * (1.f/512.f);
  }
  __syncthreads();
  float acc[16];
  #pragma unroll
  for (int bb=0;bb<16;++bb) acc[bb]=0.f;
  const float* wcol = W1 + (size_t)k0*DM + tid;
  #pragma unroll 4
  for (int i=0;i<512;++i){
    float w = wcol[(size_t)i*DM];
    #pragma unroll
    for (int bb=0;bb<16;++bb) acc[bb] = fmaf(fl[bb][i], w, acc[bb]);
  }
  #pragma unroll
  for (int bb=0;bb<16;++bb) atomicAdd(&hw_pre[bb*DM + tid], acc[bb]);
  const int colj = tid & 31, sub = tid >> 5;
  float acc2[16];
  #pragma unroll
  for (int bb=0;bb<16;++bb) acc2[bb]=0.f;
  const float* wscol = Wsm + (size_t)(k0 + sub*64)*NF + colj;
  #pragma unroll 4
  for (int i=0;i<64;++i){
    float w = wscol[(size_t)i*NF];
    #pragma unroll
    for (int bb=0;bb<16;++bb) acc2[bb] = fmaf(fl[bb][sub*64+i], w, acc2[bb]);
  }
  #pragma unroll
  for (int bb=0;bb<16;++bb) atomicAdd(&sk_pre[bb*NF + colj], acc2[bb]);
}

// ---------------- pass2b: weight GRN + LN + softmax -> weights ----------------
__global__ __launch_bounds__(64) void k_pass2b(const float* __restrict__ hw_pre, const float* __restrict__ sk_pre,
    const float* __restrict__ B1, const float* __restrict__ W2, const float* __restrict__ B2,
    const float* __restrict__ Wg, const float* __restrict__ Bg, const float* __restrict__ Bs,
    const float* __restrict__ LNg, const float* __restrict__ LNb,
    float* __restrict__ out, float* __restrict__ wsel){
  __shared__ float hw[256];
  const int tid = threadIdx.x, b = blockIdx.x;
  for (int i=tid;i<256;i+=64) hw[i] = eluf(hw_pre[b*DM+i] + B1[i]);
  __syncthreads();
  if (tid < 32){
    const int j = tid;
    float ap = B2[j], ag = Bg[j];
    #pragma unroll 4
    for (int i=0;i<256;++i){ float h = hw[i]; ap = fmaf(h, W2[i*NF+j], ap); ag = fmaf(h, Wg[i*NF+j], ag); }
    float gw = sigm(ag);
    float v = sk_pre[b*NF+j] + Bs[j] + gw*ap;
    float s1 = v;
    s1 += __shfl_xor(s1,1); s1 += __shfl_xor(s1,2); s1 += __shfl_xor(s1,4); s1 += __shfl_xor(s1,8); s1 += __shfl_xor(s1,16);
    float mean = s1*(1.f/32.f);
    float dv = v - mean;
    float s2 = dv*dv;
    s2 += __shfl_xor(s2,1); s2 += __shfl_xor(s2,2); s2 += __shfl_xor(s2,4); s2 += __shfl_xor(s2,8); s2 += __shfl_xor(s2,16);
    float wn = fmaf(dv * rsqrtf(s2*(1.f/32.f) + EPS), LNg[j], LNb[j]);
    float mx = wn;
    mx = fmaxf(mx, __shfl_xor(mx,1)); mx = fmaxf(mx, __shfl_xor(mx,2)); mx = fmaxf(mx, __shfl_xor(mx,4));
    mx = fmaxf(mx, __shfl_xor(mx,8)); mx = fmaxf(mx, __shfl_xor(mx,16));
    float e = __expf(wn - mx);
    float se = e;
    se += __shfl_xor(se,1); se += __shfl_xor(se,2); se += __shfl_xor(se,4); se += __shfl_xor(se,8); se += __shfl_xor(se,16);
    float wgt = e / se;
    out[OUT_W_OFF + b*NF + j] = wgt;
    wsel[b*NF + j] = wgt;
  }
}

// ---------------- combine: thread owns d=tid; per-f coefs in registers; no LDS ----------------
// block = (tgrp, toct): 8 tokens x 256 d; reads 32 x 4KB contiguous runs.
__global__ __launch_bounds__(256) void k_comb(const uint4* __restrict__ stk4,
    const float* __restrict__ wsel, const float* __restrict__ lng, const float* __restrict__ lnb,
    float* __restrict__ out){
  const int tid = threadIdx.x;
  const int tgrp = blockIdx.x >> 4, toct = blockIdx.x & 15;
  const int b = tgrp >> 2;
  const int d = tid;
  float wv[32];
  #pragma unroll
  for (int k=0;k<8;++k){
    float4 w4 = *(const float4*)(wsel + b*NF + k*4);
    wv[4*k] = w4.x; wv[4*k+1] = w4.y; wv[4*k+2] = w4.z; wv[4*k+3] = w4.w;
  }
  float coef[32];
  float c1 = 0.f;
  #pragma unroll
  for (int f=0;f<NF;++f){
    coef[f] = wv[f] * lng[f*DM + d];
    c1 = fmaf(wv[f], lnb[f*DM + d], c1);
  }
  const size_t base = (size_t)tgrp*131072 + (size_t)toct*256 + d;
  float acc[8];
  #pragma unroll
  for (int j=0;j<8;++j) acc[j]=0.f;
  #pragma unroll
  for (int f=0;f<NF;++f){
    uint4 v = stk4[base + (size_t)f*4096];
    f16x8 s8 = __builtin_bit_cast(f16x8, v);
    float cf = coef[f];
    #pragma unroll
    for (int j=0;j<8;++j) acc[j] = fmaf(cf, (float)s8[j], acc[j]);
  }
  const int loc4 = toct>>2, qg = (toct>>1)&1, hg = toct&1;
  const int tbase = tgrp*128 + loc4*32 + 16*hg + 4*qg;
  #pragma unroll
  for (int j=0;j<8;++j){
    int t = tbase + (j&3) + 8*(j>>2);
    out[(size_t)t*DM + d] = acc[j] + c1;
  }
}

extern "C" void kernel_launch(void* const* d_in, const int* in_sizes, int n_in,
                              void* d_out, int out_size, void* d_ws, size_t ws_size,
                              hipStream_t stream) {
  const float* x   = (const float*)d_in[0];
  const float* w1  = (const float*)d_in[1];
  const float* b1  = (const float*)d_in[2];
  const float* w2  = (const float*)d_in[3];
  const float* b2  = (const float*)d_in[4];
  const float* wgm = (const float*)d_in[5];
  const float* bg  = (const float*)d_in[6];
  const float* wsk = (const float*)d_in[7];
  const float* bsk = (const float*)d_in[8];
  const float* lng = (const float*)d_in[9];
  const float* lnb = (const float*)d_in[10];
  const float* W1  = (const float*)d_in[11];
  const float* B1  = (const float*)d_in[12];
  const float* W2  = (const float*)d_in[13];
  const float* B2  = (const float*)d_in[14];
  const float* Wg  = (const float*)d_in[15];
  const float* Bg  = (const float*)d_in[16];
  const float* Wsm = (const float*)d_in[17];
  const float* Bs  = (const float*)d_in[18];
  const float* LNg = (const float*)d_in[19];
  const float* LNb = (const float*)d_in[20];
  float* out = (float*)d_out;

  char* ws = (char*)d_ws;
  uint4* Wpk    = (uint4*)ws;                     // 4 MiB bf16-packed weights
  uint4* stk4   = (uint4*)(ws + 4194304);         // 128 MiB fp16 normalized shat0
  float* pooled = (float*)(ws + 138412032);       // 512 KiB
  float* hw_pre = (float*)(ws + 138936320);       // 16 KiB
  float* sk_pre = (float*)(ws + 138952704);       // 2 KiB
  float* wsel   = (float*)(ws + 138954752);       // 2 KiB

  (void)hipMemsetAsync(pooled, 0, 524288 + 16384 + 2048, stream);

  k_prep<<<dim3(32,8), 256, 0, stream>>>(w2, wgm, Wpk);
  k_pass1<<<dim3(256,32), 256, 0, stream>>>(x, w1, b1, b2, bg, wsk, bsk, lng, lnb,
                                            Wpk, pooled, stk4);
  k_pass2a<<<16, 256, 0, stream>>>(pooled, W1, Wsm, hw_pre, sk_pre);
  k_pass2b<<<16, 64, 0, stream>>>(hw_pre, sk_pre, B1, W2, B2, Wg, Bg, Bs, LNg, LNb, out, wsel);
  k_comb<<<1024, 256, 0, stream>>>(stk4, wsel, lng, lnb, out);
}